// Round 12
// baseline (237.477 us; speedup 1.0000x reference)
//
#include <hip/hip_runtime.h>
#include <cmath>

// ---- problem constants ----
constexpr int CIN  = 192;
constexpr int HW   = 4096;
constexpr int NIMG = 32768;
constexpr int NCLS = 8192;
constexpr int NE   = 131072;

#define EPSW 1e-4f
#define ALPHA 0.7905694150420949f    // mp_cat: Cc/sqrt(256)*0.5, Cc=sqrt(640)
#define BETA  1.5811388300841898f    // Cc/sqrt(64)*0.5
#define SILU_INV 1.6778523489932886f // 1/0.596

using bf16x8 = __attribute__((ext_vector_type(8))) __bf16;
using f32x4  = __attribute__((ext_vector_type(4))) float;

__device__ __forceinline__ ushort f2bf(float f) {   // RNE fp32->bf16
  uint u = __float_as_uint(f);
  u = (u + 0x7FFFu + ((u >> 16) & 1u)) >> 16;
  return (ushort)u;
}
__device__ __forceinline__ float bf2f(ushort h) {
  return __uint_as_float(((uint)h) << 16);
}
__device__ __forceinline__ float bflo(uint u) { return __uint_as_float(u << 16); }
__device__ __forceinline__ float bfhi(uint u) { return __uint_as_float(u & 0xFFFF0000u); }
__device__ __forceinline__ uint bfpack(float lo, float hi) {
  return (uint)f2bf(lo) | ((uint)f2bf(hi) << 16);
}
__device__ __forceinline__ float wave_red_sum(float v) {
  #pragma unroll
  for (int off = 32; off > 0; off >>= 1) v += __shfl_xor(v, off, 64);
  return v;
}
__device__ __forceinline__ int wave_red_sumi(int v) {
  #pragma unroll
  for (int off = 32; off > 0; off >>= 1) v += __shfl_xor(v, off, 64);
  return v;
}

// ---- fused prologue: wnorm (768 blk) | edge counts (512) | x transpose (512) |
// ---- class_x cvt (128) ----
struct WNA {
  const float* w[12];
  ushort* o[12];
  int F[12];
  int os[12];
  int oo[12];
};
__global__ __launch_bounds__(256) void pre_k(WNA a,
                                             const int* __restrict__ d1,
                                             const int* __restrict__ d2,
                                             int* __restrict__ c1,
                                             int* __restrict__ c2,
                                             const float* __restrict__ x,
                                             ushort* __restrict__ Xin,
                                             const float* __restrict__ clsx,
                                             ushort* __restrict__ clsb) {
  __shared__ ushort T[192 * 65];
  const int bx = blockIdx.x, t = threadIdx.x;
  if (bx < 768) {           // wnorm: 64 blocks/matrix, 4 rows/block (wave per row)
    const int wi = bx >> 6;
    const int row = ((bx & 63) << 2) + (t >> 6);
    const int lane = t & 63;
    const int F = a.F[wi];
    const float* wr = a.w[wi] + (size_t)row * F;
    float ss = 0.f;
    for (int f = lane; f < F; f += 64) { float v = wr[f]; ss += v * v; }
    ss = wave_red_sum(ss);
    const float scale = 1.0f / (EPSW * sqrtf((float)F) + sqrtf(ss));
    ushort* o = a.o[wi] + (size_t)row * a.os[wi] + a.oo[wi];
    for (int f = lane; f < F; f += 64) o[f] = f2bf(wr[f] * scale);
  } else if (bx < 1280) {   // counti
    const int e = (bx - 768) * 256 + t;
    atomicAdd(&c1[d1[e]], 1);
    atomicAdd(&c2[d2[e]], 1);
  } else if (bx < 1792) {   // x NCHW fp32 -> Xin [32768,192] bf16
    const int b2 = bx - 1280;
    const int b = b2 >> 6, hw0 = (b2 & 63) * 64;
    const float* xb = x + (size_t)b * CIN * HW;
    for (int idx = t; idx < CIN * 64; idx += 256) {
      int c = idx >> 6, p = idx & 63;
      T[c * 65 + p] = f2bf(xb[(size_t)c * HW + hw0 + p]);
    }
    __syncthreads();
    ushort* ob = Xin + ((size_t)b * HW + hw0) * CIN;
    for (int idx = t; idx < CIN * 64; idx += 256) {
      int p = idx / CIN, c = idx - p * CIN;
      ob[(size_t)p * CIN + c] = T[c * 65 + p];
    }
  } else {                  // class_x fp32 -> bf16 (1M elems, 128 blocks)
    const int b3 = bx - 1792;
    for (int i4 = b3 * 256 + t; i4 < (NCLS * 128) / 4; i4 += 128 * 256) {
      float4 v = *(const float4*)(clsx + (size_t)i4 * 4);
      ushort4 o = { f2bf(v.x), f2bf(v.y), f2bf(v.z), f2bf(v.w) };
      *(ushort4*)(clsb + (size_t)i4 * 4) = o;
    }
  }
}

// blocks 0..31: img counts, 32..39: cls. Each block scans 1024 ints.
__global__ __launch_bounds__(256) void scanA_k(const int* __restrict__ cnt,
                                               int* __restrict__ st_img,
                                               int* __restrict__ st_cls,
                                               int* __restrict__ bsum) {
  const int bid = blockIdx.x;
  const bool cls = bid >= 32;
  const int* c = cnt + (cls ? NIMG : 0);
  int* s = cls ? st_cls : st_img;
  const int base = (cls ? bid - 32 : bid) * 1024;
  const int t = threadIdx.x, lane = t & 63, wid = t >> 6;
  int4 v = *(const int4*)(c + base + t * 4);
  const int i0 = v.x, i1 = i0 + v.y, i2 = i1 + v.z, i3 = i2 + v.w;
  int x = i3;
  #pragma unroll
  for (int off = 1; off < 64; off <<= 1) {
    int y = __shfl_up(x, off, 64);
    if (lane >= off) x += y;
  }
  const int pre = x - i3;
  __shared__ int wt[4];
  if (lane == 63) wt[wid] = x;
  __syncthreads();
  int woff = 0;
  #pragma unroll
  for (int i = 0; i < 4; ++i) if (i < wid) woff += wt[i];
  const int b = woff + pre;
  int4 o = { b, b + i0, b + i1, b + i2 };
  *(int4*)(s + base + t * 4) = o;
  if (t == 255) bsum[bid] = woff + x;
}

__global__ __launch_bounds__(256) void scanC_k(const int* __restrict__ bsum,
                                               int* __restrict__ st_img,
                                               int* __restrict__ st_cls) {
  const int bid = blockIdx.x;
  const bool cls = bid >= 32;
  const int seg0 = cls ? 32 : 0;
  const int t = threadIdx.x;
  __shared__ int off_s;
  if (t < 64) {
    int v = (t < bid - seg0) ? bsum[seg0 + t] : 0;
    v = wave_red_sumi(v);
    if (t == 0) off_s = v;
  }
  __syncthreads();
  const int off = off_s;
  int* s = cls ? st_cls : st_img;
  const int base = (cls ? bid - 32 : bid) * 1024;
  int4 v = *(int4*)(s + base + t * 4);
  v.x += off; v.y += off; v.z += off; v.w += off;
  *(int4*)(s + base + t * 4) = v;
  if (bid == 0 && t == 0) { st_img[NIMG] = NE; st_cls[NCLS] = NE; }
}

__global__ void fill2_k(const int* __restrict__ dst1, const int* __restrict__ src1,
                        const int* __restrict__ st1, int* __restrict__ cur1,
                        int2* __restrict__ eix1,
                        const int* __restrict__ dst2, const int* __restrict__ src2,
                        const int* __restrict__ st2, int* __restrict__ cur2,
                        int2* __restrict__ eix2) {
  int e = blockIdx.x * 256 + threadIdx.x;
  int d = dst1[e];
  int p = atomicAdd(&cur1[d], 1);
  eix1[st1[d] + p] = make_int2(e, src1[e]);
  d = dst2[e];
  p = atomicAdd(&cur2[d], 1);
  eix2[st2[d] + p] = make_int2(e, src2[e]);
}

// ---- CSR gather-mean of H, one graph side: 2 rows/wave, 32 lanes/row ----
struct AJ {
  const ushort* Hs; const int2* eix; const int* st;
  ushort* agg; const float* EA; ushort* eam; int do_eam;
};

__device__ __forceinline__ void agg_body(const AJ J, int bx, int t) {
  const int r  = bx * 8 + (t >> 5);
  const int hl = t & 31;
  ushort* out = J.agg + (size_t)r * 256;
  const int s0 = J.st[r], s1 = J.st[r + 1];
  float a[8] = {};
  float ae0 = 0.f, ae1 = 0.f;
  for (int j = s0; j < s1; j += 4) {
    const int i1 = min(j + 1, s1 - 1), i2 = min(j + 2, s1 - 1), i3 = min(j + 3, s1 - 1);
    const int2 e0 = J.eix[j], e1 = J.eix[i1], e2 = J.eix[i2], e3 = J.eix[i3];
    const float w1 = (j + 1 < s1) ? 1.f : 0.f;
    const float w2 = (j + 2 < s1) ? 1.f : 0.f;
    const float w3 = (j + 3 < s1) ? 1.f : 0.f;
    uint4 h0 = *(const uint4*)(J.Hs + (size_t)e0.y * 256 + hl * 8);
    uint4 h1 = *(const uint4*)(J.Hs + (size_t)e1.y * 256 + hl * 8);
    uint4 h2 = *(const uint4*)(J.Hs + (size_t)e2.y * 256 + hl * 8);
    uint4 h3 = *(const uint4*)(J.Hs + (size_t)e3.y * 256 + hl * 8);
    const uint u0[4] = { h0.x, h0.y, h0.z, h0.w };
    const uint u1[4] = { h1.x, h1.y, h1.z, h1.w };
    const uint u2[4] = { h2.x, h2.y, h2.z, h2.w };
    const uint u3[4] = { h3.x, h3.y, h3.z, h3.w };
    #pragma unroll
    for (int i = 0; i < 4; ++i) {
      a[2 * i + 0] += bflo(u0[i]) + w1 * bflo(u1[i]) + w2 * bflo(u2[i]) + w3 * bflo(u3[i]);
      a[2 * i + 1] += bfhi(u0[i]) + w1 * bfhi(u1[i]) + w2 * bfhi(u2[i]) + w3 * bfhi(u3[i]);
    }
    if (J.do_eam) {
      float2 v0 = *(const float2*)(J.EA + (size_t)e0.x * 64 + hl * 2);
      float2 v1 = *(const float2*)(J.EA + (size_t)e1.x * 64 + hl * 2);
      float2 v2 = *(const float2*)(J.EA + (size_t)e2.x * 64 + hl * 2);
      float2 v3 = *(const float2*)(J.EA + (size_t)e3.x * 64 + hl * 2);
      ae0 += v0.x + w1 * v1.x + w2 * v2.x + w3 * v3.x;
      ae1 += v0.y + w1 * v1.y + w2 * v2.y + w3 * v3.y;
    }
  }
  const float inv = 1.0f / fmaxf((float)(s1 - s0), 1.0f);
  const float c = ALPHA * inv;
  uint4 o;
  o.x = bfpack(a[0] * c, a[1] * c);
  o.y = bfpack(a[2] * c, a[3] * c);
  o.z = bfpack(a[4] * c, a[5] * c);
  o.w = bfpack(a[6] * c, a[7] * c);
  *(uint4*)(out + hl * 8) = o;
  if (J.do_eam) {
    const float cb = BETA * inv;
    *(uint*)(J.eam + (size_t)r * 64 + hl * 2) = bfpack(ae0 * cb, ae1 * cb);
  }
}

// ---- row L2 normalize in place (+optional silu -> A), one side, 4 rows/block ----
struct RJ { ushort* H; ushort* A; int do_silu; };

__device__ __forceinline__ void rns_body(const RJ J, int bx, int t) {
  const int row  = bx * 4 + (t >> 6);
  const int lane = t & 63;
  ushort* H = J.H + (size_t)row * 256;
  uint2 v = *(uint2*)(H + lane * 4);
  float x0 = bflo(v.x), x1 = bfhi(v.x), x2 = bflo(v.y), x3 = bfhi(v.y);
  float ss = x0 * x0 + x1 * x1 + x2 * x2 + x3 * x3;
  ss = wave_red_sum(ss);
  const float sc = 1.0f / fmaxf(sqrtf(ss), 1e-12f);
  x0 *= sc; x1 *= sc; x2 *= sc; x3 *= sc;
  uint2 o = { bfpack(x0, x1), bfpack(x2, x3) };
  *(uint2*)(H + lane * 4) = o;
  if (J.do_silu) {
    float s0 = (x0 / (1.0f + __expf(-x0))) * SILU_INV;
    float s1 = (x1 / (1.0f + __expf(-x1))) * SILU_INV;
    float s2 = (x2 / (1.0f + __expf(-x2))) * SILU_INV;
    float s3 = (x3 / (1.0f + __expf(-x3))) * SILU_INV;
    uint2 oa = { bfpack(s0, s1), bfpack(s2, s3) };
    *(uint2*)(J.A + (size_t)row * 256 + lane * 4) = oa;
  }
}

// ---- bf16 MFMA GEMM (R3-proven core): 256 threads, tile 128x128, BK=32 ----
// a_mode 0: A bf16 [M,K]
// a_mode 2: concat k<256 AG [M,256] | 256..319 EAM [M,64] | >=320 AD [M,256]
// c_mode 0: bf16 [M,256] (+opt silu); 1: fp32 img NCHW; 2: fp32 [M,256]
__device__ __forceinline__ int lds_swz(int row, int kbyte) {
  return ((row << 6) + kbyte) ^ ((row & 7) << 4);
}

struct GJ {
  const ushort* A; const ushort* AG; const ushort* EAM; const ushort* B;
  void* O;
  int K, a_mode, c_mode, nrt, do_silu;
};

__device__ __forceinline__ void gemm_body(const GJ J, int bx, char* ldsb) {
  ushort* As = (ushort*)ldsb;            // 128 x 32 (8 KB)
  ushort* Bs = (ushort*)(ldsb + 8192);   // 128 x 32 (8 KB)
  const int t    = threadIdx.x;
  const int row0 = (bx % J.nrt) * 128;
  const int col0 = (bx / J.nrt) * 128;
  const int srow = t >> 1;            // staging row 0..127
  const int skh  = (t & 1) * 16;      // staging k offset (elements)
  const int w    = t >> 6, lane = t & 63;
  const int wr   = (w >> 1) * 64, wc = (w & 1) * 64;
  const int l15  = lane & 15, lk16 = (lane >> 4) * 16;
  const int K = J.K;
  f32x4 acc[4][4] = {};

  uint4 ar0, ar1, br0, br1;
  auto loadA = [&](int k0) {
    const int row = row0 + srow;
    const int kk = k0 + skh;
    const ushort* p;
    if (J.a_mode == 2) {
      p = (kk < 256) ? J.AG + (size_t)row * 256 + kk
        : (kk < 320) ? J.EAM + (size_t)row * 64 + (kk - 256)
                     : J.A + (size_t)row * 256 + (kk - 320);
    } else {
      p = J.A + (size_t)row * K + kk;
    }
    ar0 = *(const uint4*)(p);
    ar1 = *(const uint4*)(p + 8);
  };
  auto loadB = [&](int k0) {
    const ushort* p = J.B + (size_t)(col0 + srow) * K + k0 + skh;
    br0 = *(const uint4*)(p);
    br1 = *(const uint4*)(p + 8);
  };

  loadA(0); loadB(0);
  for (int k0 = 0; k0 < K; k0 += 32) {
    __syncthreads();
    *(uint4*)((char*)As + lds_swz(srow, skh * 2))      = ar0;
    *(uint4*)((char*)As + lds_swz(srow, skh * 2 + 16)) = ar1;
    *(uint4*)((char*)Bs + lds_swz(srow, skh * 2))      = br0;
    *(uint4*)((char*)Bs + lds_swz(srow, skh * 2 + 16)) = br1;
    __syncthreads();
    if (k0 + 32 < K) { loadA(k0 + 32); loadB(k0 + 32); }
    bf16x8 af[4], bfr[4];
    #pragma unroll
    for (int m = 0; m < 4; ++m)
      af[m] = *(const bf16x8*)((const char*)As + lds_swz(wr + m * 16 + l15, lk16));
    #pragma unroll
    for (int n = 0; n < 4; ++n)
      bfr[n] = *(const bf16x8*)((const char*)Bs + lds_swz(wc + n * 16 + l15, lk16));
    #pragma unroll
    for (int m = 0; m < 4; ++m)
      #pragma unroll
      for (int n = 0; n < 4; ++n)
        acc[m][n] = __builtin_amdgcn_mfma_f32_16x16x32_bf16(af[m], bfr[n], acc[m][n], 0, 0, 0);
  }

  ushort* Ob = (ushort*)J.O;
  float*  Of = (float*)J.O;
  #pragma unroll
  for (int m = 0; m < 4; ++m) {
    const int rbase = row0 + wr + m * 16 + (lane >> 4) * 4;
    #pragma unroll
    for (int n = 0; n < 4; ++n) {
      const int col = col0 + wc + n * 16 + l15;
      #pragma unroll
      for (int j = 0; j < 4; ++j) {
        const int r = rbase + j;
        if (J.c_mode == 0) {
          float v = acc[m][n][j];
          if (J.do_silu) v = (v / (1.0f + __expf(-v))) * SILU_INV;
          Ob[(size_t)r * 256 + col] = f2bf(v);
        } else if (J.c_mode == 1) {
          Of[((size_t)(col >> 12) * 256 + r) * 4096 + (col & 4095)] = acc[m][n][j];
        } else {
          Of[(size_t)r * 256 + col] = acc[m][n][j];
        }
      }
    }
  }
}

__global__ __launch_bounds__(256) void gemm2_k(GJ j0, GJ j1, int n0) {
  __shared__ char ldsb[16384];
  const int bx = blockIdx.x;
  if (bx < n0) gemm_body(j0, bx, ldsb);
  else         gemm_body(j1, bx - n0, ldsb);
}

__global__ __launch_bounds__(256) void gemm_agg_k(GJ g, AJ a, int ng) {
  __shared__ char ldsb[16384];
  const int bx = blockIdx.x;
  if (bx < ng) gemm_body(g, bx, ldsb);
  else         agg_body(a, bx - ng, threadIdx.x);
}

__global__ __launch_bounds__(256) void gemm_rns_k(GJ g, RJ r, int ng) {
  __shared__ char ldsb[16384];
  const int bx = blockIdx.x;
  if (bx < ng) gemm_body(g, bx, ldsb);
  else         rns_body(r, bx - ng, threadIdx.x);
}

__global__ __launch_bounds__(256) void agg_k(AJ a) {
  agg_body(a, blockIdx.x, threadIdx.x);
}

__global__ __launch_bounds__(256) void rns_k(RJ r) {
  rns_body(r, blockIdx.x, threadIdx.x);
}

extern "C" void kernel_launch(void* const* d_in, const int* in_sizes, int n_in,
                              void* d_out, int out_size, void* d_ws, size_t ws_size,
                              hipStream_t stream) {
  const float* x        = (const float*)d_in[0];
  const float* class_x  = (const float*)d_in[1];
  const float* ea_c2i   = (const float*)d_in[2];
  const float* ea_i2c   = (const float*)d_in[3];
  const int* src_c2i = (const int*)d_in[16];
  const int* dst_c2i = (const int*)d_in[17];
  const int* src_i2c = (const int*)d_in[18];
  const int* dst_i2c = (const int*)d_in[19];

  float* ws = (float*)d_ws;
  size_t off = 0;
  auto alloc = [&](size_t n) { float* p = ws + off; off += (n + 15) & ~(size_t)15; return p; };

  ushort* A_img   = (ushort*)alloc((size_t)NIMG * 128);   // bf16 [NIMG,256]
  ushort* A_cls   = (ushort*)alloc((size_t)NCLS * 128);
  ushort* H_img   = (ushort*)alloc((size_t)NIMG * 128);
  ushort* H_cls   = (ushort*)alloc((size_t)NCLS * 128);
  ushort* agg_img = (ushort*)alloc((size_t)NIMG * 128);
  ushort* agg_cls = (ushort*)alloc((size_t)NCLS * 128);
  ushort* eam_img = (ushort*)alloc((size_t)NIMG * 32);    // bf16 [NIMG,64]
  ushort* eam_cls = (ushort*)alloc((size_t)NCLS * 32);
  int* cnt       = (int*)alloc(2 * (NIMG + NCLS));        // cnt | cur
  int* cur       = cnt + (NIMG + NCLS);
  int* bsum      = (int*)alloc(48);
  int* st_img    = (int*)alloc(NIMG + 1 + NCLS + 1 + 14);
  int* st_cls    = st_img + NIMG + 1;
  int2* eix_c2i  = (int2*)alloc((size_t)NE * 2);          // {edge, src}
  int2* eix_i2c  = (int2*)alloc((size_t)NE * 2);
  ushort* wn_in_img  = (ushort*)alloc(256 * 96);
  ushort* wn_in_cls  = (ushort*)alloc(256 * 64);
  ushort* wcat0      = (ushort*)alloc(256 * 288);
  ushort* wcat1      = (ushort*)alloc(256 * 288);
  ushort* wcat2      = (ushort*)alloc(256 * 288);
  ushort* wcat3      = (ushort*)alloc(256 * 288);
  ushort* wn_out_img = (ushort*)alloc(256 * 128);
  ushort* wn_out_cls = (ushort*)alloc(256 * 128);
  // aliases: consumed by input GEMM before layer-1 agg writes hosts
  ushort* Xin      = agg_img;   // [NIMG,192] bf16
  ushort* class_bf = agg_cls;   // [NCLS,128] bf16

  const dim3 blk(256);

  // ---- prologue: memset + (wnorm | counti | x-transpose | class cvt) ----
  hipMemsetAsync(cnt, 0, (size_t)2 * (NIMG + NCLS) * sizeof(int), stream);
  WNA wa;
  const float* wsrc[12] = { (const float*)d_in[4], (const float*)d_in[5],
                            (const float*)d_in[6], (const float*)d_in[7],
                            (const float*)d_in[8], (const float*)d_in[9],
                            (const float*)d_in[10], (const float*)d_in[11],
                            (const float*)d_in[12], (const float*)d_in[13],
                            (const float*)d_in[14], (const float*)d_in[15] };
  ushort* wdst[12] = { wn_in_img, wn_in_cls, wcat0, wcat0, wcat1, wcat1,
                       wcat2, wcat2, wcat3, wcat3, wn_out_img, wn_out_cls };
  const int wF[12]  = { 192, 128, 320, 256, 320, 256, 320, 256, 320, 256, 256, 256 };
  const int wOS[12] = { 192, 128, 576, 576, 576, 576, 576, 576, 576, 576, 256, 256 };
  const int wOO[12] = { 0, 0, 0, 320, 0, 320, 0, 320, 0, 320, 0, 0 };
  for (int i = 0; i < 12; ++i) {
    wa.w[i] = wsrc[i]; wa.o[i] = wdst[i]; wa.F[i] = wF[i]; wa.os[i] = wOS[i]; wa.oo[i] = wOO[i];
  }
  pre_k<<<1920, blk, 0, stream>>>(wa, dst_c2i, dst_i2c, cnt, cnt + NIMG,
                                  x, Xin, class_x, class_bf);

  // ---- CSR scan + fill ----
  scanA_k<<<40, blk, 0, stream>>>(cnt, st_img, st_cls, bsum);
  scanC_k<<<40, blk, 0, stream>>>(bsum, st_img, st_cls);
  fill2_k<<<NE / 256, blk, 0, stream>>>(dst_c2i, src_c2i, st_img, cur, eix_c2i,
                                        dst_i2c, src_i2c, st_cls, cur + NIMG, eix_i2c);

  // ---- input projections -> silu'd A directly (H never materialized) ----
  GJ jin0 = { Xin,      nullptr, nullptr, wn_in_img, A_img, 192, 0, 0, 256, 1 };
  GJ jin1 = { class_bf, nullptr, nullptr, wn_in_cls, A_cls, 128, 0, 0, 64, 1 };
  gemm2_k<<<640, blk, 0, stream>>>(jin0, jin1, 512);

  const ushort* wc2i[2] = { wcat0, wcat2 };
  const ushort* wi2c[2] = { wcat1, wcat3 };

  // ================= layer 1 =================
  AJ aI0 = { A_cls, eix_c2i, st_img, agg_img, ea_c2i, eam_img, 1 };
  agg_k<<<NIMG / 8, blk, 0, stream>>>(aI0);

  GJ gI0 = { A_img, agg_img, eam_img, wc2i[0], H_img, 576, 2, 0, 256, 0 };
  AJ aC0 = { A_img, eix_i2c, st_cls, agg_cls, ea_i2c, eam_cls, 1 };
  gemm_agg_k<<<512 + NCLS / 8, blk, 0, stream>>>(gI0, aC0, 512);

  GJ gC0 = { A_cls, agg_cls, eam_cls, wi2c[0], H_cls, 576, 2, 0, 64, 0 };
  RJ rIs = { H_img, A_img, 1 };
  gemm_rns_k<<<128 + NIMG / 4, blk, 0, stream>>>(gC0, rIs, 128);

  RJ rCs = { H_cls, A_cls, 1 };
  rns_k<<<NCLS / 4, blk, 0, stream>>>(rCs);

  // ================= layer 2 =================
  AJ aI1 = { A_cls, eix_c2i, st_img, agg_img, nullptr, nullptr, 0 };
  agg_k<<<NIMG / 8, blk, 0, stream>>>(aI1);

  GJ gI1 = { A_img, agg_img, eam_img, wc2i[1], H_img, 576, 2, 0, 256, 0 };
  AJ aC1 = { A_img, eix_i2c, st_cls, agg_cls, nullptr, nullptr, 0 };
  gemm_agg_k<<<512 + NCLS / 8, blk, 0, stream>>>(gI1, aC1, 512);

  GJ gC1 = { A_cls, agg_cls, eam_cls, wi2c[1], H_cls, 576, 2, 0, 64, 0 };
  RJ rI1 = { H_img, nullptr, 0 };
  gemm_rns_k<<<128 + NIMG / 4, blk, 0, stream>>>(gC1, rI1, 128);

  // ---- output: [out_img || rownorm_cls] then out_cls ----
  float* out_img = (float*)d_out;
  float* out_cls = (float*)d_out + (size_t)NIMG * 256;
  GJ joI = { wn_out_img, nullptr, nullptr, H_img, out_img, 256, 0, 1, 2, 0 };
  RJ rC1 = { H_cls, nullptr, 0 };
  gemm_rns_k<<<512 + NCLS / 4, blk, 0, stream>>>(joI, rC1, 512);

  GJ joC = { H_cls, nullptr, nullptr, wn_out_cls, out_cls, 256, 0, 2, 64, 0 };
  gemm2_k<<<128, blk, 0, stream>>>(joC, joC, 128);
}

// Round 13
// 209.702 us; speedup vs baseline: 1.1324x; 1.1324x over previous
//
#include <hip/hip_runtime.h>
#include <cmath>

// ---- problem constants ----
constexpr int CIN  = 192;
constexpr int HW   = 4096;
constexpr int NIMG = 32768;
constexpr int NCLS = 8192;
constexpr int NE   = 131072;

#define EPSW 1e-4f
#define ALPHA 0.7905694150420949f    // mp_cat: Cc/sqrt(256)*0.5, Cc=sqrt(640)
#define BETA  1.5811388300841898f    // Cc/sqrt(64)*0.5
#define SILU_INV 1.6778523489932886f // 1/0.596

using bf16x8 = __attribute__((ext_vector_type(8))) __bf16;
using f32x4  = __attribute__((ext_vector_type(4))) float;

__device__ __forceinline__ ushort f2bf(float f) {   // RNE fp32->bf16
  uint u = __float_as_uint(f);
  u = (u + 0x7FFFu + ((u >> 16) & 1u)) >> 16;
  return (ushort)u;
}
__device__ __forceinline__ float bf2f(ushort h) {
  return __uint_as_float(((uint)h) << 16);
}
__device__ __forceinline__ float bflo(uint u) { return __uint_as_float(u << 16); }
__device__ __forceinline__ float bfhi(uint u) { return __uint_as_float(u & 0xFFFF0000u); }
__device__ __forceinline__ uint bfpack(float lo, float hi) {
  return (uint)f2bf(lo) | ((uint)f2bf(hi) << 16);
}
__device__ __forceinline__ float wave_red_sum(float v) {
  #pragma unroll
  for (int off = 32; off > 0; off >>= 1) v += __shfl_xor(v, off, 64);
  return v;
}
__device__ __forceinline__ int wave_red_sumi(int v) {
  #pragma unroll
  for (int off = 32; off > 0; off >>= 1) v += __shfl_xor(v, off, 64);
  return v;
}

// ---- fused prologue: wnorm (768 blk) | edge counts (512) | x transpose (512) |
// ---- class_x cvt (128) ----
struct WNA {
  const float* w[12];
  ushort* o[12];
  int F[12];
  int os[12];
  int oo[12];
};
__global__ __launch_bounds__(256) void pre_k(WNA a,
                                             const int* __restrict__ d1,
                                             const int* __restrict__ d2,
                                             int* __restrict__ c1,
                                             int* __restrict__ c2,
                                             const float* __restrict__ x,
                                             ushort* __restrict__ Xin,
                                             const float* __restrict__ clsx,
                                             ushort* __restrict__ clsb) {
  __shared__ ushort T[192 * 65];
  const int bx = blockIdx.x, t = threadIdx.x;
  if (bx < 768) {           // wnorm: 64 blocks/matrix, 4 rows/block (wave per row)
    const int wi = bx >> 6;
    const int row = ((bx & 63) << 2) + (t >> 6);
    const int lane = t & 63;
    const int F = a.F[wi];
    const float* wr = a.w[wi] + (size_t)row * F;
    float ss = 0.f;
    for (int f = lane; f < F; f += 64) { float v = wr[f]; ss += v * v; }
    ss = wave_red_sum(ss);
    const float scale = 1.0f / (EPSW * sqrtf((float)F) + sqrtf(ss));
    ushort* o = a.o[wi] + (size_t)row * a.os[wi] + a.oo[wi];
    for (int f = lane; f < F; f += 64) o[f] = f2bf(wr[f] * scale);
  } else if (bx < 1280) {   // counti
    const int e = (bx - 768) * 256 + t;
    atomicAdd(&c1[d1[e]], 1);
    atomicAdd(&c2[d2[e]], 1);
  } else if (bx < 1792) {   // x NCHW fp32 -> Xin [32768,192] bf16
    const int b2 = bx - 1280;
    const int b = b2 >> 6, hw0 = (b2 & 63) * 64;
    const float* xb = x + (size_t)b * CIN * HW;
    for (int idx = t; idx < CIN * 64; idx += 256) {
      int c = idx >> 6, p = idx & 63;
      T[c * 65 + p] = f2bf(xb[(size_t)c * HW + hw0 + p]);
    }
    __syncthreads();
    ushort* ob = Xin + ((size_t)b * HW + hw0) * CIN;
    for (int idx = t; idx < CIN * 64; idx += 256) {
      int p = idx / CIN, c = idx - p * CIN;
      ob[(size_t)p * CIN + c] = T[c * 65 + p];
    }
  } else {                  // class_x fp32 -> bf16 (1M elems, 128 blocks)
    const int b3 = bx - 1792;
    for (int i4 = b3 * 256 + t; i4 < (NCLS * 128) / 4; i4 += 128 * 256) {
      float4 v = *(const float4*)(clsx + (size_t)i4 * 4);
      ushort4 o = { f2bf(v.x), f2bf(v.y), f2bf(v.z), f2bf(v.w) };
      *(ushort4*)(clsb + (size_t)i4 * 4) = o;
    }
  }
}

// blocks 0..31: img counts, 32..39: cls. Each block scans 1024 ints.
__global__ __launch_bounds__(256) void scanA_k(const int* __restrict__ cnt,
                                               int* __restrict__ st_img,
                                               int* __restrict__ st_cls,
                                               int* __restrict__ bsum) {
  const int bid = blockIdx.x;
  const bool cls = bid >= 32;
  const int* c = cnt + (cls ? NIMG : 0);
  int* s = cls ? st_cls : st_img;
  const int base = (cls ? bid - 32 : bid) * 1024;
  const int t = threadIdx.x, lane = t & 63, wid = t >> 6;
  int4 v = *(const int4*)(c + base + t * 4);
  const int i0 = v.x, i1 = i0 + v.y, i2 = i1 + v.z, i3 = i2 + v.w;
  int x = i3;
  #pragma unroll
  for (int off = 1; off < 64; off <<= 1) {
    int y = __shfl_up(x, off, 64);
    if (lane >= off) x += y;
  }
  const int pre = x - i3;
  __shared__ int wt[4];
  if (lane == 63) wt[wid] = x;
  __syncthreads();
  int woff = 0;
  #pragma unroll
  for (int i = 0; i < 4; ++i) if (i < wid) woff += wt[i];
  const int b = woff + pre;
  int4 o = { b, b + i0, b + i1, b + i2 };
  *(int4*)(s + base + t * 4) = o;
  if (t == 255) bsum[bid] = woff + x;
}

__global__ __launch_bounds__(256) void scanC_k(const int* __restrict__ bsum,
                                               int* __restrict__ st_img,
                                               int* __restrict__ st_cls) {
  const int bid = blockIdx.x;
  const bool cls = bid >= 32;
  const int seg0 = cls ? 32 : 0;
  const int t = threadIdx.x;
  __shared__ int off_s;
  if (t < 64) {
    int v = (t < bid - seg0) ? bsum[seg0 + t] : 0;
    v = wave_red_sumi(v);
    if (t == 0) off_s = v;
  }
  __syncthreads();
  const int off = off_s;
  int* s = cls ? st_cls : st_img;
  const int base = (cls ? bid - 32 : bid) * 1024;
  int4 v = *(int4*)(s + base + t * 4);
  v.x += off; v.y += off; v.z += off; v.w += off;
  *(int4*)(s + base + t * 4) = v;
  if (bid == 0 && t == 0) { st_img[NIMG] = NE; st_cls[NCLS] = NE; }
}

// ---- CSR bucket fill (device function; fused into input-GEMM launch) ----
__device__ __forceinline__ void fill_body(
    int e, const int* __restrict__ dst1, const int* __restrict__ src1,
    const int* __restrict__ st1, int* __restrict__ cur1, int2* __restrict__ eix1,
    const int* __restrict__ dst2, const int* __restrict__ src2,
    const int* __restrict__ st2, int* __restrict__ cur2, int2* __restrict__ eix2) {
  int d = dst1[e];
  int p = atomicAdd(&cur1[d], 1);
  eix1[st1[d] + p] = make_int2(e, src1[e]);
  d = dst2[e];
  p = atomicAdd(&cur2[d], 1);
  eix2[st2[d] + p] = make_int2(e, src2[e]);
}

// ---- CSR gather-mean of H (img rows then cls rows): 2 rows/wave, 32 lanes/row ----
__global__ __launch_bounds__(256) void agg2_k(
    const ushort* __restrict__ Aimg, const ushort* __restrict__ Acls,
    const int2* __restrict__ eix_ci, const int2* __restrict__ eix_ic,
    const int* __restrict__ st_img, const int* __restrict__ st_cls,
    ushort* __restrict__ agg_img, ushort* __restrict__ agg_cls,
    const float* __restrict__ ea_ci, const float* __restrict__ ea_ic,
    ushort* __restrict__ eam_img, ushort* __restrict__ eam_cls, int do_eam) {
  const int row = blockIdx.x * 8 + (threadIdx.x >> 5);   // 8 rows per block
  const int hl  = threadIdx.x & 31;                       // half-wave lane
  const ushort* Hs; const int2* eix; const int* st; ushort* out;
  const float* EA; ushort* oute; int r;
  if (row < NIMG) { r = row;        Hs = Acls; eix = eix_ci; st = st_img;
                    out = agg_img + (size_t)r * 256; EA = ea_ci;
                    oute = eam_img + (size_t)r * 64; }
  else            { r = row - NIMG; Hs = Aimg; eix = eix_ic; st = st_cls;
                    out = agg_cls + (size_t)r * 256; EA = ea_ic;
                    oute = eam_cls + (size_t)r * 64; }
  const int s0 = st[r], s1 = st[r + 1];
  float a[8] = {};
  float ae0 = 0.f, ae1 = 0.f;
  for (int j = s0; j < s1; j += 4) {
    const int i1 = min(j + 1, s1 - 1), i2 = min(j + 2, s1 - 1), i3 = min(j + 3, s1 - 1);
    const int2 e0 = eix[j], e1 = eix[i1], e2 = eix[i2], e3 = eix[i3];
    const float w1 = (j + 1 < s1) ? 1.f : 0.f;
    const float w2 = (j + 2 < s1) ? 1.f : 0.f;
    const float w3 = (j + 3 < s1) ? 1.f : 0.f;
    uint4 h0 = *(const uint4*)(Hs + (size_t)e0.y * 256 + hl * 8);
    uint4 h1 = *(const uint4*)(Hs + (size_t)e1.y * 256 + hl * 8);
    uint4 h2 = *(const uint4*)(Hs + (size_t)e2.y * 256 + hl * 8);
    uint4 h3 = *(const uint4*)(Hs + (size_t)e3.y * 256 + hl * 8);
    const uint u0[4] = { h0.x, h0.y, h0.z, h0.w };
    const uint u1[4] = { h1.x, h1.y, h1.z, h1.w };
    const uint u2[4] = { h2.x, h2.y, h2.z, h2.w };
    const uint u3[4] = { h3.x, h3.y, h3.z, h3.w };
    #pragma unroll
    for (int i = 0; i < 4; ++i) {
      a[2 * i + 0] += bflo(u0[i]) + w1 * bflo(u1[i]) + w2 * bflo(u2[i]) + w3 * bflo(u3[i]);
      a[2 * i + 1] += bfhi(u0[i]) + w1 * bfhi(u1[i]) + w2 * bfhi(u2[i]) + w3 * bfhi(u3[i]);
    }
    if (do_eam) {
      float2 v0 = *(const float2*)(EA + (size_t)e0.x * 64 + hl * 2);
      float2 v1 = *(const float2*)(EA + (size_t)e1.x * 64 + hl * 2);
      float2 v2 = *(const float2*)(EA + (size_t)e2.x * 64 + hl * 2);
      float2 v3 = *(const float2*)(EA + (size_t)e3.x * 64 + hl * 2);
      ae0 += v0.x + w1 * v1.x + w2 * v2.x + w3 * v3.x;
      ae1 += v0.y + w1 * v1.y + w2 * v2.y + w3 * v3.y;
    }
  }
  const float inv = 1.0f / fmaxf((float)(s1 - s0), 1.0f);
  const float c = ALPHA * inv;
  uint4 o;
  o.x = bfpack(a[0] * c, a[1] * c);
  o.y = bfpack(a[2] * c, a[3] * c);
  o.z = bfpack(a[4] * c, a[5] * c);
  o.w = bfpack(a[6] * c, a[7] * c);
  *(uint4*)(out + hl * 8) = o;
  if (do_eam) {
    const float cb = BETA * inv;
    *(uint*)(oute + hl * 2) = bfpack(ae0 * cb, ae1 * cb);
  }
}

// ---- fused row L2 normalize + optional silu->A (img + cls), bf16 ----
// (the /sqrt(2) of mp_sum cancels under L2 normalization)
__global__ __launch_bounds__(256) void rns2_k(ushort* __restrict__ Hi,
                                              ushort* __restrict__ Hc,
                                              ushort* __restrict__ Ai,
                                              ushort* __restrict__ Ac,
                                              int do_silu) {
  const int row  = blockIdx.x * 4 + (threadIdx.x >> 6);
  const int lane = threadIdx.x & 63;
  ushort* H; ushort* A;
  if (row < NIMG) { H = Hi + (size_t)row * 256; A = Ai + (size_t)row * 256; }
  else { H = Hc + (size_t)(row - NIMG) * 256; A = Ac + (size_t)(row - NIMG) * 256; }
  uint2 v = *(uint2*)(H + lane * 4);
  float x0 = bflo(v.x), x1 = bfhi(v.x), x2 = bflo(v.y), x3 = bfhi(v.y);
  float ss = x0 * x0 + x1 * x1 + x2 * x2 + x3 * x3;
  ss = wave_red_sum(ss);
  const float sc = 1.0f / fmaxf(sqrtf(ss), 1e-12f);
  x0 *= sc; x1 *= sc; x2 *= sc; x3 *= sc;
  uint2 o = { bfpack(x0, x1), bfpack(x2, x3) };
  *(uint2*)(H + lane * 4) = o;
  if (do_silu) {
    float s0 = (x0 / (1.0f + __expf(-x0))) * SILU_INV;
    float s1 = (x1 / (1.0f + __expf(-x1))) * SILU_INV;
    float s2 = (x2 / (1.0f + __expf(-x2))) * SILU_INV;
    float s3 = (x3 / (1.0f + __expf(-x3))) * SILU_INV;
    uint2 oa = { bfpack(s0, s1), bfpack(s2, s3) };
    *(uint2*)(A + lane * 4) = oa;
  }
}

// ---- bf16 MFMA GEMM (R3-proven core): 256 threads, tile 128x128, BK=32,
// ---- reg-prefetch + swizzled LDS, 2 barriers/K-step. ----
// a_mode 0: A bf16 [M,K]
// a_mode 2: concat k<256 AG [M,256] | 256..319 EAM [M,64] | >=320 AD [M,256]
// c_mode 0: bf16 [M,256] (+opt silu); 1: fp32 img NCHW; 2: fp32 [M,256]
__device__ __forceinline__ int lds_swz(int row, int kbyte) {
  return ((row << 6) + kbyte) ^ ((row & 7) << 4);
}

struct GJ {
  const ushort* A; const ushort* AG; const ushort* EAM; const ushort* B;
  void* O;
  int K, a_mode, c_mode, nrt, do_silu;
};

__device__ __forceinline__ void gemm_body(const GJ J, int bx, char* ldsb) {
  ushort* As = (ushort*)ldsb;            // 128 x 32 (8 KB)
  ushort* Bs = (ushort*)(ldsb + 8192);   // 128 x 32 (8 KB)
  const int t    = threadIdx.x;
  const int row0 = (bx % J.nrt) * 128;
  const int col0 = (bx / J.nrt) * 128;
  const int srow = t >> 1;            // staging row 0..127
  const int skh  = (t & 1) * 16;      // staging k offset (elements)
  const int w    = t >> 6, lane = t & 63;
  const int wr   = (w >> 1) * 64, wc = (w & 1) * 64;
  const int l15  = lane & 15, lk16 = (lane >> 4) * 16;
  const int K = J.K;
  f32x4 acc[4][4] = {};

  uint4 ar0, ar1, br0, br1;
  auto loadA = [&](int k0) {
    const int row = row0 + srow;
    const int kk = k0 + skh;
    const ushort* p;
    if (J.a_mode == 2) {
      p = (kk < 256) ? J.AG + (size_t)row * 256 + kk
        : (kk < 320) ? J.EAM + (size_t)row * 64 + (kk - 256)
                     : J.A + (size_t)row * 256 + (kk - 320);
    } else {
      p = J.A + (size_t)row * K + kk;
    }
    ar0 = *(const uint4*)(p);
    ar1 = *(const uint4*)(p + 8);
  };
  auto loadB = [&](int k0) {
    const ushort* p = J.B + (size_t)(col0 + srow) * K + k0 + skh;
    br0 = *(const uint4*)(p);
    br1 = *(const uint4*)(p + 8);
  };

  loadA(0); loadB(0);
  for (int k0 = 0; k0 < K; k0 += 32) {
    __syncthreads();
    *(uint4*)((char*)As + lds_swz(srow, skh * 2))      = ar0;
    *(uint4*)((char*)As + lds_swz(srow, skh * 2 + 16)) = ar1;
    *(uint4*)((char*)Bs + lds_swz(srow, skh * 2))      = br0;
    *(uint4*)((char*)Bs + lds_swz(srow, skh * 2 + 16)) = br1;
    __syncthreads();
    if (k0 + 32 < K) { loadA(k0 + 32); loadB(k0 + 32); }
    bf16x8 af[4], bfr[4];
    #pragma unroll
    for (int m = 0; m < 4; ++m)
      af[m] = *(const bf16x8*)((const char*)As + lds_swz(wr + m * 16 + l15, lk16));
    #pragma unroll
    for (int n = 0; n < 4; ++n)
      bfr[n] = *(const bf16x8*)((const char*)Bs + lds_swz(wc + n * 16 + l15, lk16));
    #pragma unroll
    for (int m = 0; m < 4; ++m)
      #pragma unroll
      for (int n = 0; n < 4; ++n)
        acc[m][n] = __builtin_amdgcn_mfma_f32_16x16x32_bf16(af[m], bfr[n], acc[m][n], 0, 0, 0);
  }

  ushort* Ob = (ushort*)J.O;
  float*  Of = (float*)J.O;
  #pragma unroll
  for (int m = 0; m < 4; ++m) {
    const int rbase = row0 + wr + m * 16 + (lane >> 4) * 4;
    #pragma unroll
    for (int n = 0; n < 4; ++n) {
      const int col = col0 + wc + n * 16 + l15;
      #pragma unroll
      for (int j = 0; j < 4; ++j) {
        const int r = rbase + j;
        if (J.c_mode == 0) {
          float v = acc[m][n][j];
          if (J.do_silu) v = (v / (1.0f + __expf(-v))) * SILU_INV;
          Ob[(size_t)r * 256 + col] = f2bf(v);
        } else if (J.c_mode == 1) {
          Of[((size_t)(col >> 12) * 256 + r) * 4096 + (col & 4095)] = acc[m][n][j];
        } else {
          Of[(size_t)r * 256 + col] = acc[m][n][j];
        }
      }
    }
  }
}

__global__ __launch_bounds__(256) void gemm2_k(GJ j0, GJ j1, int n0) {
  __shared__ char ldsb[16384];
  const int bx = blockIdx.x;
  if (bx < n0) gemm_body(j0, bx, ldsb);
  else         gemm_body(j1, bx - n0, ldsb);
}

// input GEMMs (1152 = 512 img + 128 cls + 512 fill blocks)
__global__ __launch_bounds__(256) void gemm_fill_k(
    GJ j0, GJ j1,
    const int* dst1, const int* src1, const int* st1, int* cur1, int2* eix1,
    const int* dst2, const int* src2, const int* st2, int* cur2, int2* eix2) {
  __shared__ char ldsb[16384];
  const int bx = blockIdx.x;
  if (bx < 512)      gemm_body(j0, bx, ldsb);
  else if (bx < 640) gemm_body(j1, bx - 512, ldsb);
  else {
    const int e = (bx - 640) * 256 + threadIdx.x;
    fill_body(e, dst1, src1, st1, cur1, eix1, dst2, src2, st2, cur2, eix2);
  }
}

extern "C" void kernel_launch(void* const* d_in, const int* in_sizes, int n_in,
                              void* d_out, int out_size, void* d_ws, size_t ws_size,
                              hipStream_t stream) {
  const float* x        = (const float*)d_in[0];
  const float* class_x  = (const float*)d_in[1];
  const float* ea_c2i   = (const float*)d_in[2];
  const float* ea_i2c   = (const float*)d_in[3];
  const int* src_c2i = (const int*)d_in[16];
  const int* dst_c2i = (const int*)d_in[17];
  const int* src_i2c = (const int*)d_in[18];
  const int* dst_i2c = (const int*)d_in[19];

  float* ws = (float*)d_ws;
  size_t off = 0;
  auto alloc = [&](size_t n) { float* p = ws + off; off += (n + 15) & ~(size_t)15; return p; };

  ushort* A_img   = (ushort*)alloc((size_t)NIMG * 128);   // bf16 [NIMG,256]
  ushort* A_cls   = (ushort*)alloc((size_t)NCLS * 128);
  ushort* H_img   = (ushort*)alloc((size_t)NIMG * 128);
  ushort* H_cls   = (ushort*)alloc((size_t)NCLS * 128);
  ushort* agg_img = (ushort*)alloc((size_t)NIMG * 128);
  ushort* agg_cls = (ushort*)alloc((size_t)NCLS * 128);
  ushort* eam_img = (ushort*)alloc((size_t)NIMG * 32);    // bf16 [NIMG,64]
  ushort* eam_cls = (ushort*)alloc((size_t)NCLS * 32);
  int* cnt       = (int*)alloc(2 * (NIMG + NCLS));        // cnt | cur
  int* cur       = cnt + (NIMG + NCLS);
  int* bsum      = (int*)alloc(48);
  int* st_img    = (int*)alloc(NIMG + 1 + NCLS + 1 + 14);
  int* st_cls    = st_img + NIMG + 1;
  int2* eix_c2i  = (int2*)alloc((size_t)NE * 2);          // {edge, src}
  int2* eix_i2c  = (int2*)alloc((size_t)NE * 2);
  ushort* wn_in_img  = (ushort*)alloc(256 * 96);
  ushort* wn_in_cls  = (ushort*)alloc(256 * 64);
  ushort* wcat0      = (ushort*)alloc(256 * 288);
  ushort* wcat1      = (ushort*)alloc(256 * 288);
  ushort* wcat2      = (ushort*)alloc(256 * 288);
  ushort* wcat3      = (ushort*)alloc(256 * 288);
  ushort* wn_out_img = (ushort*)alloc(256 * 128);
  ushort* wn_out_cls = (ushort*)alloc(256 * 128);
  // aliases: consumed by input GEMM before layer-1 agg writes hosts
  ushort* Xin      = agg_img;   // [NIMG,192] bf16
  ushort* class_bf = agg_cls;   // [NCLS,128] bf16

  const dim3 blk(256);

  // ---- prologue: memset + (wnorm | counti | x-transpose | class cvt) ----
  hipMemsetAsync(cnt, 0, (size_t)2 * (NIMG + NCLS) * sizeof(int), stream);
  WNA wa;
  const float* wsrc[12] = { (const float*)d_in[4], (const float*)d_in[5],
                            (const float*)d_in[6], (const float*)d_in[7],
                            (const float*)d_in[8], (const float*)d_in[9],
                            (const float*)d_in[10], (const float*)d_in[11],
                            (const float*)d_in[12], (const float*)d_in[13],
                            (const float*)d_in[14], (const float*)d_in[15] };
  ushort* wdst[12] = { wn_in_img, wn_in_cls, wcat0, wcat0, wcat1, wcat1,
                       wcat2, wcat2, wcat3, wcat3, wn_out_img, wn_out_cls };
  const int wF[12]  = { 192, 128, 320, 256, 320, 256, 320, 256, 320, 256, 256, 256 };
  const int wOS[12] = { 192, 128, 576, 576, 576, 576, 576, 576, 576, 576, 256, 256 };
  const int wOO[12] = { 0, 0, 0, 320, 0, 320, 0, 320, 0, 320, 0, 0 };
  for (int i = 0; i < 12; ++i) {
    wa.w[i] = wsrc[i]; wa.o[i] = wdst[i]; wa.F[i] = wF[i]; wa.os[i] = wOS[i]; wa.oo[i] = wOO[i];
  }
  pre_k<<<1920, blk, 0, stream>>>(wa, dst_c2i, dst_i2c, cnt, cnt + NIMG,
                                  x, Xin, class_x, class_bf);

  // ---- CSR scan ----
  scanA_k<<<40, blk, 0, stream>>>(cnt, st_img, st_cls, bsum);
  scanC_k<<<40, blk, 0, stream>>>(bsum, st_img, st_cls);

  // ---- input projections (silu epilogue -> A directly) + CSR fill ----
  GJ jin0 = { Xin,      nullptr, nullptr, wn_in_img, A_img, 192, 0, 0, 256, 1 };
  GJ jin1 = { class_bf, nullptr, nullptr, wn_in_cls, A_cls, 128, 0, 0, 64, 1 };
  gemm_fill_k<<<1152, blk, 0, stream>>>(jin0, jin1,
                                        dst_c2i, src_c2i, st_img, cur, eix_c2i,
                                        dst_i2c, src_i2c, st_cls, cur + NIMG, eix_i2c);

  // ---- layers ----
  const ushort* wc2i[2] = { wcat0, wcat2 };
  const ushort* wi2c[2] = { wcat1, wcat3 };
  for (int l = 0; l < 2; ++l) {
    agg2_k<<<(NIMG + NCLS) / 8, blk, 0, stream>>>(
        A_img, A_cls, eix_c2i, eix_i2c, st_img, st_cls, agg_img, agg_cls,
        ea_c2i, ea_i2c, eam_img, eam_cls, l == 0 ? 1 : 0);
    GJ jc0 = { A_img, agg_img, eam_img, wc2i[l], H_img, 576, 2, 0, 256, 0 };
    GJ jc1 = { A_cls, agg_cls, eam_cls, wi2c[l], H_cls, 576, 2, 0, 64, 0 };
    gemm2_k<<<640, blk, 0, stream>>>(jc0, jc1, 512);
    // norm in place; layer 1 additionally emits silu'd A for layer 2
    rns2_k<<<(NIMG + NCLS) / 4, blk, 0, stream>>>(H_img, H_cls, A_img, A_cls,
                                                  l == 0 ? 1 : 0);
  }

  // ---- output projections (img swapped: A=W, B=H_img, NCHW store) ----
  float* out_img = (float*)d_out;
  float* out_cls = (float*)d_out + (size_t)NIMG * 256;
  GJ jo0 = { wn_out_img, nullptr, nullptr, H_img,      out_img, 256, 0, 1, 2, 0 };
  GJ jo1 = { H_cls,      nullptr, nullptr, wn_out_cls, out_cls, 256, 0, 2, 64, 0 };
  gemm2_k<<<640, blk, 0, stream>>>(jo0, jo1, 512);
}